// Round 12
// baseline (2812.454 us; speedup 1.0000x reference)
//
#include <hip/hip_runtime.h>
#include <hip/hip_bf16.h>

// GATv2 x3 + BN + ReLU + mean-pool + linear.
// MFMA bf16 GEMMs (BN+ReLU+finalize fused into A-load), fp32 softmax math.
// All intermediates bf16. CSR build via single-pass bucket split (8 dst
// partitions, XCD-local hist/scatter). Aggregation at the random-line
// fabric floor (~1.4 TB/s L2-miss traffic) — measured invariant R6-R11.
// N=100000 nodes, E=1.6M edges (+N self loops), F=128, H=64/32/16, G=64.

static constexpr int G_ = 64;
static constexpr float EPS_ = 1e-5f;

typedef short bfrag __attribute__((ext_vector_type(8)));   // 8 bf16 = 4 VGPR
typedef float facc  __attribute__((ext_vector_type(4)));   // 4 f32 acc

// ---------------- bf16 helpers ----------------
__device__ __forceinline__ float asfloat_(unsigned int u) {
  union { unsigned int i; float f; } c; c.i = u; return c.f;
}
__device__ __forceinline__ unsigned short f2bf(float f) {
  union { float f; unsigned int i; } c;
  c.f = f;
  unsigned int r = c.i + 0x7FFFu + ((c.i >> 16) & 1u);  // round-nearest-even
  return (unsigned short)(r >> 16);
}
__device__ __forceinline__ unsigned int pack2bf(float a, float b) {
  return (unsigned int)f2bf(a) | ((unsigned int)f2bf(b) << 16);
}

// load 4 bf16 as fp32 (8B vector load)
__device__ __forceinline__ void load_bf4(const unsigned short* p, float* f) {
  uint2 q = *reinterpret_cast<const uint2*>(p);
  f[0] = asfloat_(q.x << 16); f[1] = asfloat_(q.x & 0xFFFF0000u);
  f[2] = asfloat_(q.y << 16); f[3] = asfloat_(q.y & 0xFFFF0000u);
}

// ---------------- weight packing: Wt[col][k] bf16 (B^T fragment layout) ----
__global__ __launch_bounds__(256) void pack_all(
    const float* __restrict__ Wl1, const float* __restrict__ Wr1,
    const float* __restrict__ bl1, const float* __restrict__ br1,
    const float* __restrict__ Wl2, const float* __restrict__ Wr2,
    const float* __restrict__ bl2, const float* __restrict__ br2,
    const float* __restrict__ Wl3, const float* __restrict__ Wr3,
    const float* __restrict__ bl3, const float* __restrict__ br3,
    unsigned short* __restrict__ Wt1, float* __restrict__ bc1,
    unsigned short* __restrict__ Wt2, float* __restrict__ bc2,
    unsigned short* __restrict__ Wt3, float* __restrict__ bc3) {
  int i = blockIdx.x * 256 + threadIdx.x;
  if (i < 128 * 128) { int c = i >> 7, k = i & 127;
    Wt1[i] = f2bf((c < 64) ? Wl1[k * 64 + c] : Wr1[k * 64 + (c - 64)]); }
  if (i < 128) bc1[i] = (i < 64) ? bl1[i] : br1[i - 64];
  if (i < 64 * 64) { int c = i >> 6, k = i & 63;
    Wt2[i] = f2bf((c < 32) ? Wl2[k * 32 + c] : Wr2[k * 32 + (c - 32)]); }
  if (i < 64) bc2[i] = (i < 32) ? bl2[i] : br2[i - 32];
  if (i < 32 * 32) { int c = i >> 5, k = i & 31;
    Wt3[i] = f2bf((c < 16) ? Wl3[k * 16 + c] : Wr3[k * 16 + (c - 16)]); }
  if (i < 32) bc3[i] = (i < 16) ? bl3[i] : br3[i - 16];
}

// ---------------- CSR build: bucket split + XCD-local hist/scatter --------
// edge_split: one pass over edges; append packed (src,dst) to the dst's
// partition bucket. Wave-aggregated cursor atomics (8 per wave-iter).
__global__ __launch_bounds__(256) void edge_split(
    const int* __restrict__ ei, unsigned long long* __restrict__ bkt,
    int* __restrict__ bcnt, int E, int Etot, int N, int Ecap) {
  float scale = 8.0f / (float)N;
  int lane = threadIdx.x & 63;
  for (int i = blockIdx.x * 256 + threadIdx.x; i < Etot; i += gridDim.x * 256) {
    int src, dst;
    if (i < E) { src = ei[i]; dst = ei[E + i]; } else { src = i - E; dst = src; }
    int p = min((int)((float)dst * scale), 7);
    unsigned long long packed =
        ((unsigned long long)(unsigned)src << 32) | (unsigned)dst;
#pragma unroll
    for (int p0 = 0; p0 < 8; p0++) {
      unsigned long long mask = __ballot(p == p0);
      if (mask) {
        int leader = __ffsll((long long)mask) - 1;
        int cnt = __popcll(mask);
        int base = 0;
        if (lane == leader) base = atomicAdd(&bcnt[p0], cnt);
        base = __shfl(base, leader);
        if (p == p0) {
          int off = __popcll(mask & ((1ULL << lane) - 1ULL));
          bkt[(size_t)p0 * Ecap + base + off] = packed;
        }
      }
    }
  }
}

// blocks with blockIdx%8==p read bucket p -> deg atomics are XCD-local
__global__ __launch_bounds__(256) void bucket_hist(
    const unsigned long long* __restrict__ bkt, const int* __restrict__ bcnt,
    int* __restrict__ deg, int Ecap) {
  int p = blockIdx.x & 7;
  int q = blockIdx.x >> 3;
  int nbq = gridDim.x >> 3;
  int n = bcnt[p];
  const unsigned long long* b = &bkt[(size_t)p * Ecap];
  for (int i = q * 256 + threadIdx.x; i < n; i += nbq * 256) {
    int dst = (int)(b[i] & 0xFFFFFFFFull);
    atomicAdd(&deg[dst], 1);
  }
}

__global__ __launch_bounds__(256) void scan1(
    const int* __restrict__ deg, int* __restrict__ part, int* __restrict__ bsums, int n) {
  __shared__ int ts[256];
  int t = threadIdx.x, b = blockIdx.x;
  int base = b * 1024 + t * 4;
  int d[4];
#pragma unroll
  for (int q = 0; q < 4; q++) d[q] = (base + q < n) ? deg[base + q] : 0;
  int s = d[0] + d[1] + d[2] + d[3];
  ts[t] = s;
  __syncthreads();
  for (int o = 1; o < 256; o <<= 1) {
    int v = (t >= o) ? ts[t - o] : 0;
    __syncthreads();
    ts[t] += v;
    __syncthreads();
  }
  int incl = ts[t];
  if (t == 255) bsums[b] = incl;
  int run = incl - s;
#pragma unroll
  for (int q = 0; q < 4; q++) {
    if (base + q < n) part[base + q] = run;
    run += d[q];
  }
}

__global__ void scan2(int* bsums, int nb) {
  __shared__ int s[256];
  int t = threadIdx.x;
  int v = (t < nb) ? bsums[t] : 0;
  s[t] = v;
  __syncthreads();
  for (int o = 1; o < 256; o <<= 1) {
    int u = (t >= o) ? s[t - o] : 0;
    __syncthreads();
    s[t] += u;
    __syncthreads();
  }
  if (t < nb) bsums[t] = s[t] - v;  // exclusive
}

__global__ __launch_bounds__(256) void scan3(
    int* __restrict__ rp, int* __restrict__ cur, const int* __restrict__ bsums,
    int n, int Etot) {
  int i = blockIdx.x * 256 + threadIdx.x;
  if (i < n) {
    int v = rp[i] + bsums[i >> 10];
    rp[i] = v; cur[i] = v;
  }
  if (i == 0) rp[n] = Etot;
}

__global__ __launch_bounds__(256) void bucket_scatter(
    const unsigned long long* __restrict__ bkt, const int* __restrict__ bcnt,
    int* __restrict__ cur, int* __restrict__ ssrc, int Ecap) {
  int p = blockIdx.x & 7;
  int q = blockIdx.x >> 3;
  int nbq = gridDim.x >> 3;
  int n = bcnt[p];
  const unsigned long long* b = &bkt[(size_t)p * Ecap];
  for (int i = q * 256 + threadIdx.x; i < n; i += nbq * 256) {
    unsigned long long e = b[i];
    int dst = (int)(e & 0xFFFFFFFFull);
    int src = (int)(e >> 32);
    int pos = atomicAdd(&cur[dst], 1);
    ssrc[pos] = src;
  }
}

// ---------------- MFMA GEMM: [XL|XR][N][H] = A[N][FI] @ Wt^T + bcat -------
// AMODE 1: A fp32 -> bf16 (layer 1).
// AMODE 2: A bf16 + BN(from raw stats,gamma,beta) + ReLU (layers 2,3);
//          BN finalize computed in a per-block LDS prologue.
template <int FI, int FO, int AMODE>
__global__ __launch_bounds__(256) void gemm_mfma(
    const void* __restrict__ Ain, const float* __restrict__ stats,
    const float* __restrict__ gamma, const float* __restrict__ beta,
    const unsigned short* __restrict__ Wt, const float* __restrict__ bcat,
    unsigned short* __restrict__ XL, unsigned short* __restrict__ XR, int N) {
  constexpr int NT = FO / 16;
  constexpr int KS = FI / 32;
  constexpr int H = FO / 2;
  __shared__ float ssh[2 * FI];
  int tid = threadIdx.x;
  if constexpr (AMODE == 2) {
    if (tid < FI) {
      float inv = 1.0f / (float)N;
      float mean = stats[tid] * inv;
      float var = stats[FI + tid] * inv - mean * mean;
      float sc = gamma[tid] * rsqrtf(var + EPS_);
      ssh[tid] = sc;
      ssh[FI + tid] = beta[tid] - mean * sc;
    }
    __syncthreads();
  }
  int w = tid >> 6;
  int lr = tid & 15;
  int lg = (tid & 63) >> 4;
  int n0 = blockIdx.x * 64;
  int arow = min(n0 + w * 16 + lr, N - 1);  // clamp reads; stores masked

  facc acc[NT];
#pragma unroll
  for (int t = 0; t < NT; t++)
#pragma unroll
    for (int e = 0; e < 4; e++) acc[t][e] = 0.f;

#pragma unroll
  for (int ks = 0; ks < KS; ks++) {
    int k0 = ks * 32 + lg * 8;
    bfrag a;
    if constexpr (AMODE == 1) {
      const float* Af = (const float*)Ain;
      const float* p = &Af[(size_t)arow * FI + k0];
      float4 lo = *reinterpret_cast<const float4*>(p);
      float4 hi = *reinterpret_cast<const float4*>(p + 4);
      union { bfrag v; unsigned short u[8]; } cv;
      cv.u[0] = f2bf(lo.x); cv.u[1] = f2bf(lo.y);
      cv.u[2] = f2bf(lo.z); cv.u[3] = f2bf(lo.w);
      cv.u[4] = f2bf(hi.x); cv.u[5] = f2bf(hi.y);
      cv.u[6] = f2bf(hi.z); cv.u[7] = f2bf(hi.w);
      a = cv.v;
    } else {
      const unsigned short* Ab = (const unsigned short*)Ain;
      float f[8];
      load_bf4(&Ab[(size_t)arow * FI + k0], f);
      load_bf4(&Ab[(size_t)arow * FI + k0 + 4], f + 4);
      float4 sc0 = *reinterpret_cast<const float4*>(&ssh[k0]);
      float4 sc1 = *reinterpret_cast<const float4*>(&ssh[k0 + 4]);
      float4 sh0 = *reinterpret_cast<const float4*>(&ssh[FI + k0]);
      float4 sh1 = *reinterpret_cast<const float4*>(&ssh[FI + k0 + 4]);
      float sc[8] = {sc0.x, sc0.y, sc0.z, sc0.w, sc1.x, sc1.y, sc1.z, sc1.w};
      float sh[8] = {sh0.x, sh0.y, sh0.z, sh0.w, sh1.x, sh1.y, sh1.z, sh1.w};
      union { bfrag v; unsigned short u[8]; } cv;
#pragma unroll
      for (int e = 0; e < 8; e++)
        cv.u[e] = f2bf(fmaxf(fmaf(f[e], sc[e], sh[e]), 0.f));
      a = cv.v;
    }
#pragma unroll
    for (int t = 0; t < NT; t++) {
      bfrag b = *reinterpret_cast<const bfrag*>(&Wt[(size_t)(t * 16 + lr) * FI + k0]);
      acc[t] = __builtin_amdgcn_mfma_f32_16x16x32_bf16(a, b, acc[t], 0, 0, 0);
    }
  }

#pragma unroll
  for (int t = 0; t < NT; t++) {
    int col = t * 16 + lr;
    float bias = bcat[col];
    unsigned short* dstbuf = (t < NT / 2) ? XL : XR;
    int cc = (t < NT / 2) ? col : (col - H);
#pragma unroll
    for (int r = 0; r < 4; r++) {
      int n = n0 + w * 16 + lg * 4 + r;
      if (n < N) dstbuf[(size_t)n * H + cc] = f2bf(acc[t][r] + bias);
    }
  }
}

// ---------------- GATv2 aggregation ----------------
__device__ __forceinline__ float lrelu02(float z) {
  return fmaxf(z, 0.2f * z);
}

// v4 (H=64): 2-chain online softmax w/ defer-max; 28 VGPR, high occupancy.
template <int H>
__global__ __launch_bounds__(256) void gat_agg4(
    const unsigned short* __restrict__ XL, const unsigned short* __restrict__ XR,
    const float* __restrict__ att, const float* __restrict__ bias,
    const int* __restrict__ rp, const int* __restrict__ ssrc,
    unsigned short* __restrict__ out, int N) {
  constexpr int L = H / 4;
  constexpr int C = 64 / L;
  constexpr int STEP = 2 * C;
  int v = blockIdx.x * 4 + (threadIdx.x >> 6);
  if (v >= N) return;
  int lane = threadIdx.x & 63;
  int fl = lane % L;
  int sub = lane / L;

  float xr[4];
  load_bf4(&XR[(size_t)v * H + fl * 4], xr);
  const float4 a4 = *reinterpret_cast<const float4*>(&att[fl * 4]);
  int beg = rp[v], end = rp[v + 1];

  float mA = -3.0e38f, dA = 0.f, accA[4] = {0.f, 0.f, 0.f, 0.f};
  float mB = -3.0e38f, dB = 0.f, accB[4] = {0.f, 0.f, 0.f, 0.f};

  auto edge = [&](int j, float& m, float& d, float (&acc)[4]) {
    int u = ssrc[j];
    float xl[4];
    load_bf4(&XL[(size_t)u * H + fl * 4], xl);
    float t = a4.x * lrelu02(xl[0] + xr[0]);
    t = fmaf(a4.y, lrelu02(xl[1] + xr[1]), t);
    t = fmaf(a4.z, lrelu02(xl[2] + xr[2]), t);
    t = fmaf(a4.w, lrelu02(xl[3] + xr[3]), t);
#pragma unroll
    for (int o = L / 2; o >= 1; o >>= 1) t += __shfl_xor(t, o);
    float diff = t - m;
    if (diff > 8.f) {
      float sc = __expf(-diff);
      d *= sc;
#pragma unroll
      for (int e = 0; e < 4; e++) acc[e] *= sc;
      m = t; diff = 0.f;
    }
    float w = __expf(diff);
    d += w;
#pragma unroll
    for (int e = 0; e < 4; e++) acc[e] = fmaf(w, xl[e], acc[e]);
  };

  for (int j = beg + sub; j < end; j += STEP) {
    edge(j, mA, dA, accA);
    int j2 = j + C;
    if (j2 < end) edge(j2, mB, dB, accB);
  }

  {
    float mn = fmaxf(mA, mB);
    float s1 = __expf(mA - mn), s2 = __expf(mB - mn);
    dA = dA * s1 + dB * s2;
#pragma unroll
    for (int e = 0; e < 4; e++) accA[e] = accA[e] * s1 + accB[e] * s2;
    mA = mn;
  }

#pragma unroll
  for (int o = L; o < 64; o <<= 1) {
    float mo = __shfl_xor(mA, o);
    float d2 = __shfl_xor(dA, o);
    float a0 = __shfl_xor(accA[0], o);
    float a1 = __shfl_xor(accA[1], o);
    float a2 = __shfl_xor(accA[2], o);
    float a3 = __shfl_xor(accA[3], o);
    float mn = fmaxf(mA, mo);
    float s1 = __expf(mA - mn), s2 = __expf(mo - mn);
    dA = dA * s1 + d2 * s2;
    accA[0] = accA[0] * s1 + a0 * s2;
    accA[1] = accA[1] * s1 + a1 * s2;
    accA[2] = accA[2] * s1 + a2 * s2;
    accA[3] = accA[3] * s1 + a3 * s2;
    mA = mn;
  }

  if (lane < L) {
    float inv = 1.f / (dA + 1e-16f);
    const float4 b4 = *reinterpret_cast<const float4*>(&bias[fl * 4]);
    uint2 o;
    o.x = pack2bf(fmaf(accA[0], inv, b4.x), fmaf(accA[1], inv, b4.y));
    o.y = pack2bf(fmaf(accA[2], inv, b4.z), fmaf(accA[3], inv, b4.w));
    *reinterpret_cast<uint2*>(&out[(size_t)v * H + fl * 4]) = o;
  }
}

// v6 (H=32/16): register-buffered chunks.
template <int H, int ITER>
__global__ __launch_bounds__(256) void gat_agg6(
    const unsigned short* __restrict__ XL, const unsigned short* __restrict__ XR,
    const float* __restrict__ att, const float* __restrict__ bias,
    const int* __restrict__ rp, const int* __restrict__ ssrc,
    unsigned short* __restrict__ out, int N) {
  constexpr int L = H / 4;
  constexpr int C = 64 / L;
  constexpr int CHUNK = C * ITER;
  int v = blockIdx.x * 4 + (threadIdx.x >> 6);
  if (v >= N) return;
  int lane = threadIdx.x & 63;
  int fl = lane % L;
  int sub = lane / L;

  float xr[4];
  load_bf4(&XR[(size_t)v * H + fl * 4], xr);
  const float4 a4 = *reinterpret_cast<const float4*>(&att[fl * 4]);
  int beg = rp[v], end = rp[v + 1];

  float m = -3.0e38f, d = 0.f, acc[4] = {0.f, 0.f, 0.f, 0.f};

  for (int cb = beg; cb < end; cb += CHUNK) {
    float xb[ITER][4];
    float tl[ITER];
    float mc = -3.0e38f;
#pragma unroll
    for (int it = 0; it < ITER; it++) {
      int j = cb + it * C + sub;
      bool valid = (j < end);
      int jj = valid ? j : (end - 1);
      int u = ssrc[jj];
      load_bf4(&XL[(size_t)u * H + fl * 4], xb[it]);
      float t = a4.x * lrelu02(xb[it][0] + xr[0]);
      t = fmaf(a4.y, lrelu02(xb[it][1] + xr[1]), t);
      t = fmaf(a4.z, lrelu02(xb[it][2] + xr[2]), t);
      t = fmaf(a4.w, lrelu02(xb[it][3] + xr[3]), t);
#pragma unroll
      for (int o = L / 2; o >= 1; o >>= 1) t += __shfl_xor(t, o);
      tl[it] = valid ? t : -3.0e38f;
      mc = fmaxf(mc, tl[it]);
    }
#pragma unroll
    for (int o = L; o < 64; o <<= 1) mc = fmaxf(mc, __shfl_xor(mc, o));

    float mn = fmaxf(m, mc);
    float sc = __expf(m - mn);
    d *= sc;
#pragma unroll
    for (int e = 0; e < 4; e++) acc[e] *= sc;
    m = mn;

#pragma unroll
    for (int it = 0; it < ITER; it++) {
      float w = __expf(tl[it] - m);
      d += w;
#pragma unroll
      for (int e = 0; e < 4; e++) acc[e] = fmaf(w, xb[it][e], acc[e]);
    }
  }

#pragma unroll
  for (int o = L; o < 64; o <<= 1) {
    d += __shfl_xor(d, o);
#pragma unroll
    for (int e = 0; e < 4; e++) acc[e] += __shfl_xor(acc[e], o);
  }

  if (lane < L) {
    float inv = 1.f / (d + 1e-16f);
    const float4 b4 = *reinterpret_cast<const float4*>(&bias[fl * 4]);
    uint2 o;
    o.x = pack2bf(fmaf(acc[0], inv, b4.x), fmaf(acc[1], inv, b4.y));
    o.y = pack2bf(fmaf(acc[2], inv, b4.z), fmaf(acc[3], inv, b4.w));
    *reinterpret_cast<uint2*>(&out[(size_t)v * H + fl * 4]) = o;
  }
}

// ---------------- BatchNorm stats over bf16 input ----------------
template <int H>
__global__ __launch_bounds__(256) void bn_stats_b(
    const unsigned short* __restrict__ X, float* __restrict__ stats, int N) {
  constexpr int P = H / 2;        // feature pairs
  constexpr int RPB = 256 / P;    // rows per iter per block
  __shared__ float lsa[256], lsb[256], lqa[256], lqb[256];
  int tid = threadIdx.x;
  int p = tid % P;
  int r0 = blockIdx.x * RPB + tid / P;
  float sa = 0.f, sb = 0.f, qa = 0.f, qb = 0.f;
  for (int n = r0; n < N; n += gridDim.x * RPB) {
    unsigned int u = *reinterpret_cast<const unsigned int*>(&X[(size_t)n * H + p * 2]);
    float a = asfloat_(u << 16), b = asfloat_(u & 0xFFFF0000u);
    sa += a; qa += a * a; sb += b; qb += b * b;
  }
  lsa[tid] = sa; lsb[tid] = sb; lqa[tid] = qa; lqb[tid] = qb;
  __syncthreads();
  if (tid < P) {
    for (int g = 1; g < RPB; g++) {
      sa += lsa[tid + g * P]; sb += lsb[tid + g * P];
      qa += lqa[tid + g * P]; qb += lqb[tid + g * P];
    }
    atomicAdd(&stats[2 * tid], sa);
    atomicAdd(&stats[2 * tid + 1], sb);
    atomicAdd(&stats[H + 2 * tid], qa);
    atomicAdd(&stats[H + 2 * tid + 1], qb);
  }
}

// ---------------- fused BN(finalize)+ReLU + mean-pool, then final linear --
__global__ __launch_bounds__(256) void pool_kernel(
    const unsigned short* __restrict__ X, const float* __restrict__ stats,
    const float* __restrict__ gamma, const float* __restrict__ beta,
    const int* __restrict__ batch, float* __restrict__ pool,
    float* __restrict__ cnt, int N) {
  __shared__ float lp[G_ * 16];
  __shared__ float lc[G_];
  int tid = threadIdx.x;
  for (int j = tid; j < G_ * 16; j += 256) lp[j] = 0.f;
  if (tid < G_) lc[tid] = 0.f;
  __syncthreads();
  // this thread's fixed feature pair
  int pp = (blockIdx.x * 256 + tid) & 7;
  float invN = 1.0f / (float)N;
  float m0 = stats[2 * pp] * invN, m1 = stats[2 * pp + 1] * invN;
  float v0 = stats[16 + 2 * pp] * invN - m0 * m0;
  float v1 = stats[16 + 2 * pp + 1] * invN - m1 * m1;
  float sc0 = gamma[2 * pp] * rsqrtf(v0 + EPS_);
  float sc1 = gamma[2 * pp + 1] * rsqrtf(v1 + EPS_);
  float sh0 = beta[2 * pp] - m0 * sc0;
  float sh1 = beta[2 * pp + 1] - m1 * sc1;
  int tot = N * 8;
  for (int i = blockIdx.x * 256 + tid; i < tot; i += gridDim.x * 256) {
    int n = i >> 3;
    int g = batch[n];
    unsigned int u = *reinterpret_cast<const unsigned int*>(&X[(size_t)n * 16 + pp * 2]);
    float a = fmaxf(fmaf(asfloat_(u << 16), sc0, sh0), 0.f);
    float b = fmaxf(fmaf(asfloat_(u & 0xFFFF0000u), sc1, sh1), 0.f);
    atomicAdd(&lp[g * 16 + 2 * pp], a);
    atomicAdd(&lp[g * 16 + 2 * pp + 1], b);
    if (pp == 0) atomicAdd(&lc[g], 1.0f);
  }
  __syncthreads();
  for (int j = tid; j < G_ * 16; j += 256) atomicAdd(&pool[j], lp[j]);
  if (tid < G_) atomicAdd(&cnt[tid], lc[tid]);
}

__global__ void final_linear(
    const float* __restrict__ pool, const float* __restrict__ cnt,
    const float* __restrict__ linW, const float* __restrict__ linb,
    float* __restrict__ out) {
  int g = threadIdx.x;
  if (g < G_) {
    float c = fmaxf(cnt[g], 1.0f);
    float acc = 0.f;
    for (int h = 0; h < 16; h++) acc += (pool[g * 16 + h] / c) * linW[h];
    out[g] = acc + linb[0];
  }
}

// ---------------- launch ----------------
extern "C" void kernel_launch(void* const* d_in, const int* in_sizes, int n_in,
                              void* d_out, int out_size, void* d_ws, size_t ws_size,
                              hipStream_t stream) {
  const float* x = (const float*)d_in[0];
  const int* ei = (const int*)d_in[1];
  const int* batch = (const int*)d_in[2];
  const int N = in_sizes[0] / 128;
  const int E = in_sizes[1] / 2;
  const int Etot = E + N;
  const int Ecap = Etot / 8 + 65536;

  char* wsb = (char*)d_ws;
  size_t off = 0;
  auto alloc = [&](size_t bytes) -> void* {
    void* p = wsb + off;
    off += (bytes + 255) & ~(size_t)255;
    return p;
  };
  unsigned short* XLb = (unsigned short*)alloc((size_t)64 * N * 2);  // xl bf16
  unsigned short* XRb = (unsigned short*)alloc((size_t)64 * N * 2);  // xr bf16
  unsigned short* R2b = (unsigned short*)alloc((size_t)64 * N * 2);  // agg out bf16
  int* row_ptr = (int*)alloc((size_t)(N + 1) * 4);
  int* cursor = (int*)alloc((size_t)N * 4);
  int* bsums = (int*)alloc(4096);
  int* ssrc = (int*)alloc((size_t)Etot * 4);
  unsigned long long* bkt = (unsigned long long*)alloc((size_t)8 * Ecap * 8);
  unsigned short* Wt1 = (unsigned short*)alloc(16384 * 2);
  float* bc1 = (float*)alloc(128 * 4);
  unsigned short* Wt2 = (unsigned short*)alloc(4096 * 2);
  float* bc2 = (float*)alloc(64 * 4);
  unsigned short* Wt3 = (unsigned short*)alloc(1024 * 2);
  float* bc3 = (float*)alloc(32 * 4);
  // zeroed region: deg[N] | bcnt[8] | stats1[128] | stats2[128] | stats3[128] | pool | cnt
  size_t zelems = (size_t)N + 8 + 3 * 128 + G_ * 16 + G_;
  char* zb = (char*)alloc(zelems * 4);
  int* deg = (int*)zb;
  int* bcnt = deg + N;
  float* stats1 = (float*)(bcnt + 8);
  float* stats2 = stats1 + 128;
  float* stats3 = stats2 + 128;
  float* pool = stats3 + 128;
  float* cnt = pool + G_ * 16;

  const float* Wl1 = (const float*)d_in[3];  const float* bl1 = (const float*)d_in[4];
  const float* Wr1 = (const float*)d_in[5];  const float* br1 = (const float*)d_in[6];
  const float* att1 = (const float*)d_in[7]; const float* bias1 = (const float*)d_in[8];
  const float* g1 = (const float*)d_in[9];   const float* b1 = (const float*)d_in[10];
  const float* Wl2 = (const float*)d_in[11]; const float* bl2 = (const float*)d_in[12];
  const float* Wr2 = (const float*)d_in[13]; const float* br2 = (const float*)d_in[14];
  const float* att2 = (const float*)d_in[15]; const float* bias2 = (const float*)d_in[16];
  const float* g2 = (const float*)d_in[17];  const float* b2 = (const float*)d_in[18];
  const float* Wl3 = (const float*)d_in[19]; const float* bl3 = (const float*)d_in[20];
  const float* Wr3 = (const float*)d_in[21]; const float* br3 = (const float*)d_in[22];
  const float* att3 = (const float*)d_in[23]; const float* bias3 = (const float*)d_in[24];
  const float* g3 = (const float*)d_in[25];  const float* b3 = (const float*)d_in[26];
  const float* linW = (const float*)d_in[27]; const float* linb = (const float*)d_in[28];
  float* out = (float*)d_out;

  int nb = (N + 1023) / 1024;
  int nnodeblk = (N + 3) / 4;
  int ngemm = (N + 63) / 64;

  // weights + zero scratch
  pack_all<<<64, 256, 0, stream>>>(Wl1, Wr1, bl1, br1, Wl2, Wr2, bl2, br2,
                                   Wl3, Wr3, bl3, br3, Wt1, bc1, Wt2, bc2, Wt3, bc3);
  hipMemsetAsync(zb, 0, zelems * 4, stream);

  // CSR build: bucket split, then XCD-local hist + scatter
  edge_split<<<2048, 256, 0, stream>>>(ei, bkt, bcnt, E, Etot, N, Ecap);
  bucket_hist<<<2048, 256, 0, stream>>>(bkt, bcnt, deg, Ecap);
  scan1<<<nb, 256, 0, stream>>>(deg, row_ptr, bsums, N);
  scan2<<<1, 256, 0, stream>>>(bsums, nb);
  scan3<<<(N + 255) / 256, 256, 0, stream>>>(row_ptr, cursor, bsums, N, Etot);
  bucket_scatter<<<2048, 256, 0, stream>>>(bkt, bcnt, cursor, ssrc, Ecap);

  // ---- layer 1 ----
  gemm_mfma<128, 128, 1><<<ngemm, 256, 0, stream>>>(
      x, nullptr, nullptr, nullptr, Wt1, bc1, XLb, XRb, N);
  gat_agg4<64><<<nnodeblk, 256, 0, stream>>>(XLb, XRb, att1, bias1, row_ptr, ssrc, R2b, N);
  bn_stats_b<64><<<512, 256, 0, stream>>>(R2b, stats1, N);

  // ---- layer 2 (BN finalize+apply+ReLU fused into GEMM A-load) ----
  gemm_mfma<64, 64, 2><<<ngemm, 256, 0, stream>>>(
      R2b, stats1, g1, b1, Wt2, bc2, XLb, XRb, N);
  gat_agg6<32, 4><<<nnodeblk, 256, 0, stream>>>(XLb, XRb, att2, bias2, row_ptr, ssrc, R2b, N);
  bn_stats_b<32><<<512, 256, 0, stream>>>(R2b, stats2, N);

  // ---- layer 3 ----
  gemm_mfma<32, 32, 2><<<ngemm, 256, 0, stream>>>(
      R2b, stats2, g2, b2, Wt3, bc3, XLb, XRb, N);
  gat_agg6<16, 2><<<nnodeblk, 256, 0, stream>>>(XLb, XRb, att3, bias3, row_ptr, ssrc, R2b, N);
  bn_stats_b<16><<<512, 256, 0, stream>>>(R2b, stats3, N);

  // ---- fused BN+ReLU+pool + linear ----
  pool_kernel<<<512, 256, 0, stream>>>(R2b, stats3, g3, b3, batch, pool, cnt, N);
  final_linear<<<1, 64, 0, stream>>>(pool, cnt, linW, linb, out);
}

// Round 13
// 537.475 us; speedup vs baseline: 5.2327x; 5.2327x over previous
//
#include <hip/hip_runtime.h>
#include <hip/hip_bf16.h>

// GATv2 x3 + BN + ReLU + mean-pool + linear.
// MFMA bf16 GEMMs (BN+ReLU+finalize fused into A-load), fp32 softmax math.
// All intermediates bf16. CSR build: deterministic 3-phase bucket split
// (count -> scan -> LDS-cursor write; NO global atomics on allocation),
// then XCD-local hist/scatter. Aggregation at the random-line fabric floor
// (~1.4 TB/s L2-miss traffic) — measured invariant R6-R11.
// N=100000 nodes, E=1.6M edges (+N self loops), F=128, H=64/32/16, G=64.

static constexpr int G_ = 64;
static constexpr float EPS_ = 1e-5f;
static constexpr int NBC = 256;   // blocks for csr count/write phases

typedef short bfrag __attribute__((ext_vector_type(8)));   // 8 bf16 = 4 VGPR
typedef float facc  __attribute__((ext_vector_type(4)));   // 4 f32 acc

// ---------------- bf16 helpers ----------------
__device__ __forceinline__ float asfloat_(unsigned int u) {
  union { unsigned int i; float f; } c; c.i = u; return c.f;
}
__device__ __forceinline__ unsigned short f2bf(float f) {
  union { float f; unsigned int i; } c;
  c.f = f;
  unsigned int r = c.i + 0x7FFFu + ((c.i >> 16) & 1u);  // round-nearest-even
  return (unsigned short)(r >> 16);
}
__device__ __forceinline__ unsigned int pack2bf(float a, float b) {
  return (unsigned int)f2bf(a) | ((unsigned int)f2bf(b) << 16);
}

// load 4 bf16 as fp32 (8B vector load)
__device__ __forceinline__ void load_bf4(const unsigned short* p, float* f) {
  uint2 q = *reinterpret_cast<const uint2*>(p);
  f[0] = asfloat_(q.x << 16); f[1] = asfloat_(q.x & 0xFFFF0000u);
  f[2] = asfloat_(q.y << 16); f[3] = asfloat_(q.y & 0xFFFF0000u);
}

// ---------------- weight packing: Wt[col][k] bf16 (B^T fragment layout) ----
__global__ __launch_bounds__(256) void pack_all(
    const float* __restrict__ Wl1, const float* __restrict__ Wr1,
    const float* __restrict__ bl1, const float* __restrict__ br1,
    const float* __restrict__ Wl2, const float* __restrict__ Wr2,
    const float* __restrict__ bl2, const float* __restrict__ br2,
    const float* __restrict__ Wl3, const float* __restrict__ Wr3,
    const float* __restrict__ bl3, const float* __restrict__ br3,
    unsigned short* __restrict__ Wt1, float* __restrict__ bc1,
    unsigned short* __restrict__ Wt2, float* __restrict__ bc2,
    unsigned short* __restrict__ Wt3, float* __restrict__ bc3) {
  int i = blockIdx.x * 256 + threadIdx.x;
  if (i < 128 * 128) { int c = i >> 7, k = i & 127;
    Wt1[i] = f2bf((c < 64) ? Wl1[k * 64 + c] : Wr1[k * 64 + (c - 64)]); }
  if (i < 128) bc1[i] = (i < 64) ? bl1[i] : br1[i - 64];
  if (i < 64 * 64) { int c = i >> 6, k = i & 63;
    Wt2[i] = f2bf((c < 32) ? Wl2[k * 32 + c] : Wr2[k * 32 + (c - 32)]); }
  if (i < 64) bc2[i] = (i < 32) ? bl2[i] : br2[i - 32];
  if (i < 32 * 32) { int c = i >> 5, k = i & 31;
    Wt3[i] = f2bf((c < 16) ? Wl3[k * 16 + c] : Wr3[k * 16 + (c - 16)]); }
  if (i < 32) bc3[i] = (i < 16) ? bl3[i] : br3[i - 16];
}

// ---------------- CSR build: deterministic bucket pipeline ----------------
// Phase 1: per-block per-partition counts (wave ballot -> LDS hist).
__global__ __launch_bounds__(256) void csr_count(
    const int* __restrict__ ei, int* __restrict__ cnts,
    int E, int Etot, int N, int T) {
  __shared__ int hist[8];
  int b = blockIdx.x;
  if (threadIdx.x < 8) hist[threadIdx.x] = 0;
  __syncthreads();
  int lane = threadIdx.x & 63;
  int start = b * T, end = min(start + T, Etot);
  float scale = 8.0f / (float)N;
  for (int i = start + threadIdx.x; i < end; i += 256) {
    int dst = (i < E) ? ei[E + i] : (i - E);
    int p = min((int)((float)dst * scale), 7);
#pragma unroll
    for (int p0 = 0; p0 < 8; p0++) {
      unsigned long long mask = __ballot(p == p0);
      if (mask) {
        int leader = __ffsll((long long)mask) - 1;
        if (lane == leader) atomicAdd(&hist[p0], __popcll(mask));
      }
    }
  }
  __syncthreads();
  if (threadIdx.x < 8) cnts[threadIdx.x * NBC + b] = hist[threadIdx.x];
}

// Phase 2: one block, 8 waves; cnts[p][b] -> absolute exclusive offsets,
// base[p] = partition starts, base[8] = Etot.
__global__ void csr_offsets(int* __restrict__ cnts, int* __restrict__ base, int Etot) {
  __shared__ int tot[8];
  int w = threadIdx.x >> 6, lane = threadIdx.x & 63;
  int idx0 = w * NBC + lane * 4;
  int v0 = cnts[idx0], v1 = cnts[idx0 + 1], v2 = cnts[idx0 + 2], v3 = cnts[idx0 + 3];
  int s = v0 + v1 + v2 + v3;
  int incl = s;
  for (int o = 1; o < 64; o <<= 1) {
    int t = __shfl_up(incl, o);
    if (lane >= o) incl += t;
  }
  int excl = incl - s;
  if (lane == 63) tot[w] = incl;
  __syncthreads();
  if (threadIdx.x == 0) {
    int r = 0;
    for (int p = 0; p < 8; p++) { int t = tot[p]; tot[p] = r; r += t; }
  }
  __syncthreads();
  int o = tot[w] + excl;
  cnts[idx0] = o; o += v0;
  cnts[idx0 + 1] = o; o += v1;
  cnts[idx0 + 2] = o; o += v2;
  cnts[idx0 + 3] = o; o += v3;
  if (threadIdx.x < 8) base[threadIdx.x] = tot[threadIdx.x];
  if (threadIdx.x == 0) base[8] = Etot;
}

// Phase 3: re-read tile, append packed (src,dst) via LDS cursors.
__global__ __launch_bounds__(256) void csr_write(
    const int* __restrict__ ei, const int* __restrict__ cnts,
    unsigned long long* __restrict__ bkt, int E, int Etot, int N, int T) {
  __shared__ int cur[8];
  int b = blockIdx.x;
  if (threadIdx.x < 8) cur[threadIdx.x] = cnts[threadIdx.x * NBC + b];
  __syncthreads();
  int lane = threadIdx.x & 63;
  int start = b * T, end = min(start + T, Etot);
  float scale = 8.0f / (float)N;
  for (int i = start + threadIdx.x; i < end; i += 256) {
    int src, dst;
    if (i < E) { src = ei[i]; dst = ei[E + i]; } else { src = i - E; dst = src; }
    int p = min((int)((float)dst * scale), 7);
    unsigned long long packed =
        ((unsigned long long)(unsigned)src << 32) | (unsigned)dst;
#pragma unroll
    for (int p0 = 0; p0 < 8; p0++) {
      unsigned long long mask = __ballot(p == p0);
      if (mask) {
        int leader = __ffsll((long long)mask) - 1;
        int cnt = __popcll(mask);
        int pos0 = 0;
        if (lane == leader) pos0 = atomicAdd(&cur[p0], cnt);
        pos0 = __shfl(pos0, leader);
        if (p == p0) {
          int off = __popcll(mask & ((1ULL << lane) - 1ULL));
          bkt[pos0 + off] = packed;
        }
      }
    }
  }
}

// blocks with blockIdx%8==p read bucket p -> deg atomics are XCD-local
__global__ __launch_bounds__(256) void bucket_hist(
    const unsigned long long* __restrict__ bkt, const int* __restrict__ base,
    int* __restrict__ deg) {
  int p = blockIdx.x & 7;
  int q = blockIdx.x >> 3;
  int nbq = gridDim.x >> 3;
  int s = base[p], e = base[p + 1];
  for (int i = s + q * 256 + threadIdx.x; i < e; i += nbq * 256) {
    int dst = (int)(bkt[i] & 0xFFFFFFFFull);
    atomicAdd(&deg[dst], 1);
  }
}

__global__ __launch_bounds__(256) void scan1(
    const int* __restrict__ deg, int* __restrict__ part, int* __restrict__ bsums, int n) {
  __shared__ int ts[256];
  int t = threadIdx.x, b = blockIdx.x;
  int base = b * 1024 + t * 4;
  int d[4];
#pragma unroll
  for (int q = 0; q < 4; q++) d[q] = (base + q < n) ? deg[base + q] : 0;
  int s = d[0] + d[1] + d[2] + d[3];
  ts[t] = s;
  __syncthreads();
  for (int o = 1; o < 256; o <<= 1) {
    int v = (t >= o) ? ts[t - o] : 0;
    __syncthreads();
    ts[t] += v;
    __syncthreads();
  }
  int incl = ts[t];
  if (t == 255) bsums[b] = incl;
  int run = incl - s;
#pragma unroll
  for (int q = 0; q < 4; q++) {
    if (base + q < n) part[base + q] = run;
    run += d[q];
  }
}

__global__ void scan2(int* bsums, int nb) {
  __shared__ int s[256];
  int t = threadIdx.x;
  int v = (t < nb) ? bsums[t] : 0;
  s[t] = v;
  __syncthreads();
  for (int o = 1; o < 256; o <<= 1) {
    int u = (t >= o) ? s[t - o] : 0;
    __syncthreads();
    s[t] += u;
    __syncthreads();
  }
  if (t < nb) bsums[t] = s[t] - v;  // exclusive
}

__global__ __launch_bounds__(256) void scan3(
    int* __restrict__ rp, int* __restrict__ cur, const int* __restrict__ bsums,
    int n, int Etot) {
  int i = blockIdx.x * 256 + threadIdx.x;
  if (i < n) {
    int v = rp[i] + bsums[i >> 10];
    rp[i] = v; cur[i] = v;
  }
  if (i == 0) rp[n] = Etot;
}

__global__ __launch_bounds__(256) void bucket_scatter(
    const unsigned long long* __restrict__ bkt, const int* __restrict__ base,
    int* __restrict__ cur, int* __restrict__ ssrc) {
  int p = blockIdx.x & 7;
  int q = blockIdx.x >> 3;
  int nbq = gridDim.x >> 3;
  int s = base[p], e = base[p + 1];
  for (int i = s + q * 256 + threadIdx.x; i < e; i += nbq * 256) {
    unsigned long long ed = bkt[i];
    int dst = (int)(ed & 0xFFFFFFFFull);
    int src = (int)(ed >> 32);
    int pos = atomicAdd(&cur[dst], 1);
    ssrc[pos] = src;
  }
}

// ---------------- MFMA GEMM: [XL|XR][N][H] = A[N][FI] @ Wt^T + bcat -------
// AMODE 1: A fp32 -> bf16 (layer 1).
// AMODE 2: A bf16 + BN(from raw stats,gamma,beta) + ReLU (layers 2,3);
//          BN finalize computed in a per-block LDS prologue.
template <int FI, int FO, int AMODE>
__global__ __launch_bounds__(256) void gemm_mfma(
    const void* __restrict__ Ain, const float* __restrict__ stats,
    const float* __restrict__ gamma, const float* __restrict__ beta,
    const unsigned short* __restrict__ Wt, const float* __restrict__ bcat,
    unsigned short* __restrict__ XL, unsigned short* __restrict__ XR, int N) {
  constexpr int NT = FO / 16;
  constexpr int KS = FI / 32;
  constexpr int H = FO / 2;
  __shared__ float ssh[2 * FI];
  int tid = threadIdx.x;
  if constexpr (AMODE == 2) {
    if (tid < FI) {
      float inv = 1.0f / (float)N;
      float mean = stats[tid] * inv;
      float var = stats[FI + tid] * inv - mean * mean;
      float sc = gamma[tid] * rsqrtf(var + EPS_);
      ssh[tid] = sc;
      ssh[FI + tid] = beta[tid] - mean * sc;
    }
    __syncthreads();
  }
  int w = tid >> 6;
  int lr = tid & 15;
  int lg = (tid & 63) >> 4;
  int n0 = blockIdx.x * 64;
  int arow = min(n0 + w * 16 + lr, N - 1);  // clamp reads; stores masked

  facc acc[NT];
#pragma unroll
  for (int t = 0; t < NT; t++)
#pragma unroll
    for (int e = 0; e < 4; e++) acc[t][e] = 0.f;

#pragma unroll
  for (int ks = 0; ks < KS; ks++) {
    int k0 = ks * 32 + lg * 8;
    bfrag a;
    if constexpr (AMODE == 1) {
      const float* Af = (const float*)Ain;
      const float* p = &Af[(size_t)arow * FI + k0];
      float4 lo = *reinterpret_cast<const float4*>(p);
      float4 hi = *reinterpret_cast<const float4*>(p + 4);
      union { bfrag v; unsigned short u[8]; } cv;
      cv.u[0] = f2bf(lo.x); cv.u[1] = f2bf(lo.y);
      cv.u[2] = f2bf(lo.z); cv.u[3] = f2bf(lo.w);
      cv.u[4] = f2bf(hi.x); cv.u[5] = f2bf(hi.y);
      cv.u[6] = f2bf(hi.z); cv.u[7] = f2bf(hi.w);
      a = cv.v;
    } else {
      const unsigned short* Ab = (const unsigned short*)Ain;
      float f[8];
      load_bf4(&Ab[(size_t)arow * FI + k0], f);
      load_bf4(&Ab[(size_t)arow * FI + k0 + 4], f + 4);
      float4 sc0 = *reinterpret_cast<const float4*>(&ssh[k0]);
      float4 sc1 = *reinterpret_cast<const float4*>(&ssh[k0 + 4]);
      float4 sh0 = *reinterpret_cast<const float4*>(&ssh[FI + k0]);
      float4 sh1 = *reinterpret_cast<const float4*>(&ssh[FI + k0 + 4]);
      float sc[8] = {sc0.x, sc0.y, sc0.z, sc0.w, sc1.x, sc1.y, sc1.z, sc1.w};
      float sh[8] = {sh0.x, sh0.y, sh0.z, sh0.w, sh1.x, sh1.y, sh1.z, sh1.w};
      union { bfrag v; unsigned short u[8]; } cv;
#pragma unroll
      for (int e = 0; e < 8; e++)
        cv.u[e] = f2bf(fmaxf(fmaf(f[e], sc[e], sh[e]), 0.f));
      a = cv.v;
    }
#pragma unroll
    for (int t = 0; t < NT; t++) {
      bfrag b = *reinterpret_cast<const bfrag*>(&Wt[(size_t)(t * 16 + lr) * FI + k0]);
      acc[t] = __builtin_amdgcn_mfma_f32_16x16x32_bf16(a, b, acc[t], 0, 0, 0);
    }
  }

#pragma unroll
  for (int t = 0; t < NT; t++) {
    int col = t * 16 + lr;
    float bias = bcat[col];
    unsigned short* dstbuf = (t < NT / 2) ? XL : XR;
    int cc = (t < NT / 2) ? col : (col - H);
#pragma unroll
    for (int r = 0; r < 4; r++) {
      int n = n0 + w * 16 + lg * 4 + r;
      if (n < N) dstbuf[(size_t)n * H + cc] = f2bf(acc[t][r] + bias);
    }
  }
}

// ---------------- GATv2 aggregation ----------------
__device__ __forceinline__ float lrelu02(float z) {
  return fmaxf(z, 0.2f * z);
}

// v4 (H=64): 2-chain online softmax w/ defer-max; 28 VGPR, high occupancy.
template <int H>
__global__ __launch_bounds__(256) void gat_agg4(
    const unsigned short* __restrict__ XL, const unsigned short* __restrict__ XR,
    const float* __restrict__ att, const float* __restrict__ bias,
    const int* __restrict__ rp, const int* __restrict__ ssrc,
    unsigned short* __restrict__ out, int N) {
  constexpr int L = H / 4;
  constexpr int C = 64 / L;
  constexpr int STEP = 2 * C;
  int v = blockIdx.x * 4 + (threadIdx.x >> 6);
  if (v >= N) return;
  int lane = threadIdx.x & 63;
  int fl = lane % L;
  int sub = lane / L;

  float xr[4];
  load_bf4(&XR[(size_t)v * H + fl * 4], xr);
  const float4 a4 = *reinterpret_cast<const float4*>(&att[fl * 4]);
  int beg = rp[v], end = rp[v + 1];

  float mA = -3.0e38f, dA = 0.f, accA[4] = {0.f, 0.f, 0.f, 0.f};
  float mB = -3.0e38f, dB = 0.f, accB[4] = {0.f, 0.f, 0.f, 0.f};

  auto edge = [&](int j, float& m, float& d, float (&acc)[4]) {
    int u = ssrc[j];
    float xl[4];
    load_bf4(&XL[(size_t)u * H + fl * 4], xl);
    float t = a4.x * lrelu02(xl[0] + xr[0]);
    t = fmaf(a4.y, lrelu02(xl[1] + xr[1]), t);
    t = fmaf(a4.z, lrelu02(xl[2] + xr[2]), t);
    t = fmaf(a4.w, lrelu02(xl[3] + xr[3]), t);
#pragma unroll
    for (int o = L / 2; o >= 1; o >>= 1) t += __shfl_xor(t, o);
    float diff = t - m;
    if (diff > 8.f) {
      float sc = __expf(-diff);
      d *= sc;
#pragma unroll
      for (int e = 0; e < 4; e++) acc[e] *= sc;
      m = t; diff = 0.f;
    }
    float w = __expf(diff);
    d += w;
#pragma unroll
    for (int e = 0; e < 4; e++) acc[e] = fmaf(w, xl[e], acc[e]);
  };

  for (int j = beg + sub; j < end; j += STEP) {
    edge(j, mA, dA, accA);
    int j2 = j + C;
    if (j2 < end) edge(j2, mB, dB, accB);
  }

  {
    float mn = fmaxf(mA, mB);
    float s1 = __expf(mA - mn), s2 = __expf(mB - mn);
    dA = dA * s1 + dB * s2;
#pragma unroll
    for (int e = 0; e < 4; e++) accA[e] = accA[e] * s1 + accB[e] * s2;
    mA = mn;
  }

#pragma unroll
  for (int o = L; o < 64; o <<= 1) {
    float mo = __shfl_xor(mA, o);
    float d2 = __shfl_xor(dA, o);
    float a0 = __shfl_xor(accA[0], o);
    float a1 = __shfl_xor(accA[1], o);
    float a2 = __shfl_xor(accA[2], o);
    float a3 = __shfl_xor(accA[3], o);
    float mn = fmaxf(mA, mo);
    float s1 = __expf(mA - mn), s2 = __expf(mo - mn);
    dA = dA * s1 + d2 * s2;
    accA[0] = accA[0] * s1 + a0 * s2;
    accA[1] = accA[1] * s1 + a1 * s2;
    accA[2] = accA[2] * s1 + a2 * s2;
    accA[3] = accA[3] * s1 + a3 * s2;
    mA = mn;
  }

  if (lane < L) {
    float inv = 1.f / (dA + 1e-16f);
    const float4 b4 = *reinterpret_cast<const float4*>(&bias[fl * 4]);
    uint2 o;
    o.x = pack2bf(fmaf(accA[0], inv, b4.x), fmaf(accA[1], inv, b4.y));
    o.y = pack2bf(fmaf(accA[2], inv, b4.z), fmaf(accA[3], inv, b4.w));
    *reinterpret_cast<uint2*>(&out[(size_t)v * H + fl * 4]) = o;
  }
}

// v6 (H=32/16): register-buffered chunks.
template <int H, int ITER>
__global__ __launch_bounds__(256) void gat_agg6(
    const unsigned short* __restrict__ XL, const unsigned short* __restrict__ XR,
    const float* __restrict__ att, const float* __restrict__ bias,
    const int* __restrict__ rp, const int* __restrict__ ssrc,
    unsigned short* __restrict__ out, int N) {
  constexpr int L = H / 4;
  constexpr int C = 64 / L;
  constexpr int CHUNK = C * ITER;
  int v = blockIdx.x * 4 + (threadIdx.x >> 6);
  if (v >= N) return;
  int lane = threadIdx.x & 63;
  int fl = lane % L;
  int sub = lane / L;

  float xr[4];
  load_bf4(&XR[(size_t)v * H + fl * 4], xr);
  const float4 a4 = *reinterpret_cast<const float4*>(&att[fl * 4]);
  int beg = rp[v], end = rp[v + 1];

  float m = -3.0e38f, d = 0.f, acc[4] = {0.f, 0.f, 0.f, 0.f};

  for (int cb = beg; cb < end; cb += CHUNK) {
    float xb[ITER][4];
    float tl[ITER];
    float mc = -3.0e38f;
#pragma unroll
    for (int it = 0; it < ITER; it++) {
      int j = cb + it * C + sub;
      bool valid = (j < end);
      int jj = valid ? j : (end - 1);
      int u = ssrc[jj];
      load_bf4(&XL[(size_t)u * H + fl * 4], xb[it]);
      float t = a4.x * lrelu02(xb[it][0] + xr[0]);
      t = fmaf(a4.y, lrelu02(xb[it][1] + xr[1]), t);
      t = fmaf(a4.z, lrelu02(xb[it][2] + xr[2]), t);
      t = fmaf(a4.w, lrelu02(xb[it][3] + xr[3]), t);
#pragma unroll
      for (int o = L / 2; o >= 1; o >>= 1) t += __shfl_xor(t, o);
      tl[it] = valid ? t : -3.0e38f;
      mc = fmaxf(mc, tl[it]);
    }
#pragma unroll
    for (int o = L; o < 64; o <<= 1) mc = fmaxf(mc, __shfl_xor(mc, o));

    float mn = fmaxf(m, mc);
    float sc = __expf(m - mn);
    d *= sc;
#pragma unroll
    for (int e = 0; e < 4; e++) acc[e] *= sc;
    m = mn;

#pragma unroll
    for (int it = 0; it < ITER; it++) {
      float w = __expf(tl[it] - m);
      d += w;
#pragma unroll
      for (int e = 0; e < 4; e++) acc[e] = fmaf(w, xb[it][e], acc[e]);
    }
  }

#pragma unroll
  for (int o = L; o < 64; o <<= 1) {
    d += __shfl_xor(d, o);
#pragma unroll
    for (int e = 0; e < 4; e++) acc[e] += __shfl_xor(acc[e], o);
  }

  if (lane < L) {
    float inv = 1.f / (d + 1e-16f);
    const float4 b4 = *reinterpret_cast<const float4*>(&bias[fl * 4]);
    uint2 o;
    o.x = pack2bf(fmaf(acc[0], inv, b4.x), fmaf(acc[1], inv, b4.y));
    o.y = pack2bf(fmaf(acc[2], inv, b4.z), fmaf(acc[3], inv, b4.w));
    *reinterpret_cast<uint2*>(&out[(size_t)v * H + fl * 4]) = o;
  }
}

// ---------------- BatchNorm stats over bf16 input ----------------
template <int H>
__global__ __launch_bounds__(256) void bn_stats_b(
    const unsigned short* __restrict__ X, float* __restrict__ stats, int N) {
  constexpr int P = H / 2;        // feature pairs
  constexpr int RPB = 256 / P;    // rows per iter per block
  __shared__ float lsa[256], lsb[256], lqa[256], lqb[256];
  int tid = threadIdx.x;
  int p = tid % P;
  int r0 = blockIdx.x * RPB + tid / P;
  float sa = 0.f, sb = 0.f, qa = 0.f, qb = 0.f;
  for (int n = r0; n < N; n += gridDim.x * RPB) {
    unsigned int u = *reinterpret_cast<const unsigned int*>(&X[(size_t)n * H + p * 2]);
    float a = asfloat_(u << 16), b = asfloat_(u & 0xFFFF0000u);
    sa += a; qa += a * a; sb += b; qb += b * b;
  }
  lsa[tid] = sa; lsb[tid] = sb; lqa[tid] = qa; lqb[tid] = qb;
  __syncthreads();
  if (tid < P) {
    for (int g = 1; g < RPB; g++) {
      sa += lsa[tid + g * P]; sb += lsb[tid + g * P];
      qa += lqa[tid + g * P]; qb += lqb[tid + g * P];
    }
    atomicAdd(&stats[2 * tid], sa);
    atomicAdd(&stats[2 * tid + 1], sb);
    atomicAdd(&stats[H + 2 * tid], qa);
    atomicAdd(&stats[H + 2 * tid + 1], qb);
  }
}

// ---------------- fused BN(finalize)+ReLU + mean-pool, then final linear --
__global__ __launch_bounds__(256) void pool_kernel(
    const unsigned short* __restrict__ X, const float* __restrict__ stats,
    const float* __restrict__ gamma, const float* __restrict__ beta,
    const int* __restrict__ batch, float* __restrict__ pool,
    float* __restrict__ cnt, int N) {
  __shared__ float lp[G_ * 16];
  __shared__ float lc[G_];
  int tid = threadIdx.x;
  for (int j = tid; j < G_ * 16; j += 256) lp[j] = 0.f;
  if (tid < G_) lc[tid] = 0.f;
  __syncthreads();
  // this thread's fixed feature pair
  int pp = (blockIdx.x * 256 + tid) & 7;
  float invN = 1.0f / (float)N;
  float m0 = stats[2 * pp] * invN, m1 = stats[2 * pp + 1] * invN;
  float v0 = stats[16 + 2 * pp] * invN - m0 * m0;
  float v1 = stats[16 + 2 * pp + 1] * invN - m1 * m1;
  float sc0 = gamma[2 * pp] * rsqrtf(v0 + EPS_);
  float sc1 = gamma[2 * pp + 1] * rsqrtf(v1 + EPS_);
  float sh0 = beta[2 * pp] - m0 * sc0;
  float sh1 = beta[2 * pp + 1] - m1 * sc1;
  int tot = N * 8;
  for (int i = blockIdx.x * 256 + tid; i < tot; i += gridDim.x * 256) {
    int n = i >> 3;
    int g = batch[n];
    unsigned int u = *reinterpret_cast<const unsigned int*>(&X[(size_t)n * 16 + pp * 2]);
    float a = fmaxf(fmaf(asfloat_(u << 16), sc0, sh0), 0.f);
    float b = fmaxf(fmaf(asfloat_(u & 0xFFFF0000u), sc1, sh1), 0.f);
    atomicAdd(&lp[g * 16 + 2 * pp], a);
    atomicAdd(&lp[g * 16 + 2 * pp + 1], b);
    if (pp == 0) atomicAdd(&lc[g], 1.0f);
  }
  __syncthreads();
  for (int j = tid; j < G_ * 16; j += 256) atomicAdd(&pool[j], lp[j]);
  if (tid < G_) atomicAdd(&cnt[tid], lc[tid]);
}

__global__ void final_linear(
    const float* __restrict__ pool, const float* __restrict__ cnt,
    const float* __restrict__ linW, const float* __restrict__ linb,
    float* __restrict__ out) {
  int g = threadIdx.x;
  if (g < G_) {
    float c = fmaxf(cnt[g], 1.0f);
    float acc = 0.f;
    for (int h = 0; h < 16; h++) acc += (pool[g * 16 + h] / c) * linW[h];
    out[g] = acc + linb[0];
  }
}

// ---------------- launch ----------------
extern "C" void kernel_launch(void* const* d_in, const int* in_sizes, int n_in,
                              void* d_out, int out_size, void* d_ws, size_t ws_size,
                              hipStream_t stream) {
  const float* x = (const float*)d_in[0];
  const int* ei = (const int*)d_in[1];
  const int* batch = (const int*)d_in[2];
  const int N = in_sizes[0] / 128;
  const int E = in_sizes[1] / 2;
  const int Etot = E + N;
  const int T = (Etot + NBC - 1) / NBC;

  char* wsb = (char*)d_ws;
  size_t off = 0;
  auto alloc = [&](size_t bytes) -> void* {
    void* p = wsb + off;
    off += (bytes + 255) & ~(size_t)255;
    return p;
  };
  unsigned short* XLb = (unsigned short*)alloc((size_t)64 * N * 2);  // xl bf16
  unsigned short* XRb = (unsigned short*)alloc((size_t)64 * N * 2);  // xr bf16
  unsigned short* R2b = (unsigned short*)alloc((size_t)64 * N * 2);  // agg out bf16
  int* row_ptr = (int*)alloc((size_t)(N + 1) * 4);
  int* cursor = (int*)alloc((size_t)N * 4);
  int* bsums = (int*)alloc(4096);
  int* ssrc = (int*)alloc((size_t)Etot * 4);
  unsigned long long* bkt = (unsigned long long*)alloc((size_t)Etot * 8);
  int* cnts = (int*)alloc(8 * NBC * 4);
  int* pbase = (int*)alloc(9 * 4);
  unsigned short* Wt1 = (unsigned short*)alloc(16384 * 2);
  float* bc1 = (float*)alloc(128 * 4);
  unsigned short* Wt2 = (unsigned short*)alloc(4096 * 2);
  float* bc2 = (float*)alloc(64 * 4);
  unsigned short* Wt3 = (unsigned short*)alloc(1024 * 2);
  float* bc3 = (float*)alloc(32 * 4);
  // zeroed region: deg[N] | stats1[128] | stats2[128] | stats3[128] | pool | cnt
  size_t zelems = (size_t)N + 3 * 128 + G_ * 16 + G_;
  char* zb = (char*)alloc(zelems * 4);
  int* deg = (int*)zb;
  float* stats1 = (float*)(zb + (size_t)N * 4);
  float* stats2 = stats1 + 128;
  float* stats3 = stats2 + 128;
  float* pool = stats3 + 128;
  float* cnt = pool + G_ * 16;

  const float* Wl1 = (const float*)d_in[3];  const float* bl1 = (const float*)d_in[4];
  const float* Wr1 = (const float*)d_in[5];  const float* br1 = (const float*)d_in[6];
  const float* att1 = (const float*)d_in[7]; const float* bias1 = (const float*)d_in[8];
  const float* g1 = (const float*)d_in[9];   const float* b1 = (const float*)d_in[10];
  const float* Wl2 = (const float*)d_in[11]; const float* bl2 = (const float*)d_in[12];
  const float* Wr2 = (const float*)d_in[13]; const float* br2 = (const float*)d_in[14];
  const float* att2 = (const float*)d_in[15]; const float* bias2 = (const float*)d_in[16];
  const float* g2 = (const float*)d_in[17];  const float* b2 = (const float*)d_in[18];
  const float* Wl3 = (const float*)d_in[19]; const float* bl3 = (const float*)d_in[20];
  const float* Wr3 = (const float*)d_in[21]; const float* br3 = (const float*)d_in[22];
  const float* att3 = (const float*)d_in[23]; const float* bias3 = (const float*)d_in[24];
  const float* g3 = (const float*)d_in[25];  const float* b3 = (const float*)d_in[26];
  const float* linW = (const float*)d_in[27]; const float* linb = (const float*)d_in[28];
  float* out = (float*)d_out;

  int nb = (N + 1023) / 1024;
  int nnodeblk = (N + 3) / 4;
  int ngemm = (N + 63) / 64;

  // weights + zero scratch
  pack_all<<<64, 256, 0, stream>>>(Wl1, Wr1, bl1, br1, Wl2, Wr2, bl2, br2,
                                   Wl3, Wr3, bl3, br3, Wt1, bc1, Wt2, bc2, Wt3, bc3);
  hipMemsetAsync(zb, 0, zelems * 4, stream);

  // CSR build: deterministic bucket split, then XCD-local hist + scatter
  csr_count<<<NBC, 256, 0, stream>>>(ei, cnts, E, Etot, N, T);
  csr_offsets<<<1, 512, 0, stream>>>(cnts, pbase, Etot);
  csr_write<<<NBC, 256, 0, stream>>>(ei, cnts, bkt, E, Etot, N, T);
  bucket_hist<<<2048, 256, 0, stream>>>(bkt, pbase, deg);
  scan1<<<nb, 256, 0, stream>>>(deg, row_ptr, bsums, N);
  scan2<<<1, 256, 0, stream>>>(bsums, nb);
  scan3<<<(N + 255) / 256, 256, 0, stream>>>(row_ptr, cursor, bsums, N, Etot);
  bucket_scatter<<<2048, 256, 0, stream>>>(bkt, pbase, cursor, ssrc);

  // ---- layer 1 ----
  gemm_mfma<128, 128, 1><<<ngemm, 256, 0, stream>>>(
      x, nullptr, nullptr, nullptr, Wt1, bc1, XLb, XRb, N);
  gat_agg4<64><<<nnodeblk, 256, 0, stream>>>(XLb, XRb, att1, bias1, row_ptr, ssrc, R2b, N);
  bn_stats_b<64><<<512, 256, 0, stream>>>(R2b, stats1, N);

  // ---- layer 2 (BN finalize+apply+ReLU fused into GEMM A-load) ----
  gemm_mfma<64, 64, 2><<<ngemm, 256, 0, stream>>>(
      R2b, stats1, g1, b1, Wt2, bc2, XLb, XRb, N);
  gat_agg6<32, 4><<<nnodeblk, 256, 0, stream>>>(XLb, XRb, att2, bias2, row_ptr, ssrc, R2b, N);
  bn_stats_b<32><<<512, 256, 0, stream>>>(R2b, stats2, N);

  // ---- layer 3 ----
  gemm_mfma<32, 32, 2><<<ngemm, 256, 0, stream>>>(
      R2b, stats2, g2, b2, Wt3, bc3, XLb, XRb, N);
  gat_agg6<16, 2><<<nnodeblk, 256, 0, stream>>>(XLb, XRb, att3, bias3, row_ptr, ssrc, R2b, N);
  bn_stats_b<16><<<512, 256, 0, stream>>>(R2b, stats3, N);

  // ---- fused BN+ReLU+pool + linear ----
  pool_kernel<<<512, 256, 0, stream>>>(R2b, stats3, g3, b3, batch, pool, cnt, N);
  final_linear<<<1, 64, 0, stream>>>(pool, cnt, linW, linb, out);
}

// Round 14
// 500.627 us; speedup vs baseline: 5.6179x; 1.0736x over previous
//
#include <hip/hip_runtime.h>
#include <hip/hip_bf16.h>

// GATv2 x3 + BN + ReLU + mean-pool + linear.
// Best-measured configuration (R10 pipeline + agg4 for H=64):
// MFMA bf16 GEMMs (no LDS, BN+ReLU fused into A-load), fp32 softmax math,
// xl/xr split bf16, fp32 agg output. Aggregation at the random-64B-line
// HBM floor (~1.1-1.4 TB/s FETCH) — measured invariant R6-R13.
// N=100000 nodes, E=1.6M edges (+N self loops), F=128, H=64/32/16, G=64.

static constexpr int G_ = 64;

typedef short bfrag __attribute__((ext_vector_type(8)));   // 8 bf16 = 4 VGPR
typedef float facc  __attribute__((ext_vector_type(4)));   // 4 f32 acc

// ---------------- bf16 helpers ----------------
__device__ __forceinline__ float asfloat_(unsigned int u) {
  union { unsigned int i; float f; } c; c.i = u; return c.f;
}
__device__ __forceinline__ unsigned short f2bf(float f) {
  union { float f; unsigned int i; } c;
  c.f = f;
  unsigned int r = c.i + 0x7FFFu + ((c.i >> 16) & 1u);  // round-nearest-even
  return (unsigned short)(r >> 16);
}

// load 4 bf16 as fp32 (8B vector load)
__device__ __forceinline__ void load_bf4(const unsigned short* p, float* f) {
  uint2 q = *reinterpret_cast<const uint2*>(p);
  f[0] = asfloat_(q.x << 16); f[1] = asfloat_(q.x & 0xFFFF0000u);
  f[2] = asfloat_(q.y << 16); f[3] = asfloat_(q.y & 0xFFFF0000u);
}

// ---------------- weight packing: Wt[col][k] bf16 (B^T fragment layout) ----
__global__ __launch_bounds__(256) void pack_all(
    const float* __restrict__ Wl1, const float* __restrict__ Wr1,
    const float* __restrict__ bl1, const float* __restrict__ br1,
    const float* __restrict__ Wl2, const float* __restrict__ Wr2,
    const float* __restrict__ bl2, const float* __restrict__ br2,
    const float* __restrict__ Wl3, const float* __restrict__ Wr3,
    const float* __restrict__ bl3, const float* __restrict__ br3,
    unsigned short* __restrict__ Wt1, float* __restrict__ bc1,
    unsigned short* __restrict__ Wt2, float* __restrict__ bc2,
    unsigned short* __restrict__ Wt3, float* __restrict__ bc3) {
  int i = blockIdx.x * 256 + threadIdx.x;
  if (i < 128 * 128) { int c = i >> 7, k = i & 127;
    Wt1[i] = f2bf((c < 64) ? Wl1[k * 64 + c] : Wr1[k * 64 + (c - 64)]); }
  if (i < 128) bc1[i] = (i < 64) ? bl1[i] : br1[i - 64];
  if (i < 64 * 64) { int c = i >> 6, k = i & 63;
    Wt2[i] = f2bf((c < 32) ? Wl2[k * 32 + c] : Wr2[k * 32 + (c - 32)]); }
  if (i < 64) bc2[i] = (i < 32) ? bl2[i] : br2[i - 32];
  if (i < 32 * 32) { int c = i >> 5, k = i & 31;
    Wt3[i] = f2bf((c < 16) ? Wl3[k * 16 + c] : Wr3[k * 16 + (c - 16)]); }
  if (i < 32) bc3[i] = (i < 16) ? bl3[i] : br3[i - 16];
}

// ---------------- CSR build (XCD-partitioned by dst range) ----------------
__global__ __launch_bounds__(256) void edge_hist(
    const int* __restrict__ ei, int* __restrict__ deg, int E, int Etot, int N) {
  int p = blockIdx.x & 7;
  int q = blockIdx.x >> 3;
  int nbq = gridDim.x >> 3;
  float scale = 8.0f / (float)N;
  for (int i = q * 256 + threadIdx.x; i < Etot; i += nbq * 256) {
    int dst = (i < E) ? ei[E + i] : (i - E);
    int pp = min((int)((float)dst * scale), 7);
    if (pp == p) atomicAdd(&deg[dst], 1);
  }
}

__global__ __launch_bounds__(256) void scan1(
    const int* __restrict__ deg, int* __restrict__ part, int* __restrict__ bsums, int n) {
  __shared__ int ts[256];
  int t = threadIdx.x, b = blockIdx.x;
  int base = b * 1024 + t * 4;
  int d[4];
#pragma unroll
  for (int q = 0; q < 4; q++) d[q] = (base + q < n) ? deg[base + q] : 0;
  int s = d[0] + d[1] + d[2] + d[3];
  ts[t] = s;
  __syncthreads();
  for (int o = 1; o < 256; o <<= 1) {
    int v = (t >= o) ? ts[t - o] : 0;
    __syncthreads();
    ts[t] += v;
    __syncthreads();
  }
  int incl = ts[t];
  if (t == 255) bsums[b] = incl;
  int run = incl - s;
#pragma unroll
  for (int q = 0; q < 4; q++) {
    if (base + q < n) part[base + q] = run;
    run += d[q];
  }
}

__global__ void scan2(int* bsums, int nb) {
  __shared__ int s[256];
  int t = threadIdx.x;
  int v = (t < nb) ? bsums[t] : 0;
  s[t] = v;
  __syncthreads();
  for (int o = 1; o < 256; o <<= 1) {
    int u = (t >= o) ? s[t - o] : 0;
    __syncthreads();
    s[t] += u;
    __syncthreads();
  }
  if (t < nb) bsums[t] = s[t] - v;  // exclusive
}

__global__ __launch_bounds__(256) void scan3(
    int* __restrict__ rp, int* __restrict__ cur, const int* __restrict__ bsums,
    int n, int Etot) {
  int i = blockIdx.x * 256 + threadIdx.x;
  if (i < n) {
    int v = rp[i] + bsums[i >> 10];
    rp[i] = v; cur[i] = v;
  }
  if (i == 0) rp[n] = Etot;
}

__global__ __launch_bounds__(256) void scatter_edges(
    const int* __restrict__ ei, int* __restrict__ cur, int* __restrict__ ssrc,
    int E, int Etot, int N) {
  int p = blockIdx.x & 7;
  int q = blockIdx.x >> 3;
  int nbq = gridDim.x >> 3;
  float scale = 8.0f / (float)N;
  for (int i = q * 256 + threadIdx.x; i < Etot; i += nbq * 256) {
    int dst = (i < E) ? ei[E + i] : (i - E);
    int pp = min((int)((float)dst * scale), 7);
    if (pp != p) continue;
    int src = (i < E) ? ei[i] : (i - E);
    int pos = atomicAdd(&cur[dst], 1);
    ssrc[pos] = src;
  }
}

// ---------------- MFMA GEMM: [XL|XR][N][H] = A[N][FI] @ Wt^T + bcat -------
// AMODE 1: A fp32 -> bf16 (layer 1).
// AMODE 2: A fp32 + BN(scale=ssb[k], shift=ssb[FI+k]) + ReLU (layers 2,3).
template <int FI, int FO, int AMODE>
__global__ __launch_bounds__(256) void gemm_mfma(
    const void* __restrict__ Ain, const float* __restrict__ ssb,
    const unsigned short* __restrict__ Wt, const float* __restrict__ bcat,
    unsigned short* __restrict__ XL, unsigned short* __restrict__ XR, int N) {
  constexpr int NT = FO / 16;
  constexpr int KS = FI / 32;
  constexpr int H = FO / 2;
  int tid = threadIdx.x;
  int w = tid >> 6;
  int lr = tid & 15;
  int lg = (tid & 63) >> 4;
  int n0 = blockIdx.x * 64;
  int arow = min(n0 + w * 16 + lr, N - 1);  // clamp reads; stores masked

  facc acc[NT];
#pragma unroll
  for (int t = 0; t < NT; t++)
#pragma unroll
    for (int e = 0; e < 4; e++) acc[t][e] = 0.f;

#pragma unroll
  for (int ks = 0; ks < KS; ks++) {
    int k0 = ks * 32 + lg * 8;
    const float* Af = (const float*)Ain;
    const float* p = &Af[(size_t)arow * FI + k0];
    float4 lo = *reinterpret_cast<const float4*>(p);
    float4 hi = *reinterpret_cast<const float4*>(p + 4);
    float f[8] = {lo.x, lo.y, lo.z, lo.w, hi.x, hi.y, hi.z, hi.w};
    if constexpr (AMODE == 2) {
      float4 sc0 = *reinterpret_cast<const float4*>(&ssb[k0]);
      float4 sc1 = *reinterpret_cast<const float4*>(&ssb[k0 + 4]);
      float4 sh0 = *reinterpret_cast<const float4*>(&ssb[FI + k0]);
      float4 sh1 = *reinterpret_cast<const float4*>(&ssb[FI + k0 + 4]);
      float sc[8] = {sc0.x, sc0.y, sc0.z, sc0.w, sc1.x, sc1.y, sc1.z, sc1.w};
      float sh[8] = {sh0.x, sh0.y, sh0.z, sh0.w, sh1.x, sh1.y, sh1.z, sh1.w};
#pragma unroll
      for (int e = 0; e < 8; e++) f[e] = fmaxf(fmaf(f[e], sc[e], sh[e]), 0.f);
    }
    bfrag a;
    union { bfrag v; unsigned short u[8]; } cv;
#pragma unroll
    for (int e = 0; e < 8; e++) cv.u[e] = f2bf(f[e]);
    a = cv.v;
#pragma unroll
    for (int t = 0; t < NT; t++) {
      bfrag b = *reinterpret_cast<const bfrag*>(&Wt[(size_t)(t * 16 + lr) * FI + k0]);
      acc[t] = __builtin_amdgcn_mfma_f32_16x16x32_bf16(a, b, acc[t], 0, 0, 0);
    }
  }

#pragma unroll
  for (int t = 0; t < NT; t++) {
    int col = t * 16 + lr;
    float bias = bcat[col];
    unsigned short* dstbuf = (t < NT / 2) ? XL : XR;
    int cc = (t < NT / 2) ? col : (col - H);
#pragma unroll
    for (int r = 0; r < 4; r++) {
      int n = n0 + w * 16 + lg * 4 + r;
      if (n < N) dstbuf[(size_t)n * H + cc] = f2bf(acc[t][r] + bias);
    }
  }
}

// ---------------- GATv2 aggregation ----------------
__device__ __forceinline__ float lrelu02(float z) {
  return fmaxf(z, 0.2f * z);
}

// v4 (H=64): 2-chain online softmax w/ defer-max; 28 VGPR, high occupancy.
template <int H>
__global__ __launch_bounds__(256) void gat_agg4(
    const unsigned short* __restrict__ XL, const unsigned short* __restrict__ XR,
    const float* __restrict__ att, const float* __restrict__ bias,
    const int* __restrict__ rp, const int* __restrict__ ssrc,
    float* __restrict__ out, int N) {
  constexpr int L = H / 4;
  constexpr int C = 64 / L;
  constexpr int STEP = 2 * C;
  int v = blockIdx.x * 4 + (threadIdx.x >> 6);
  if (v >= N) return;
  int lane = threadIdx.x & 63;
  int fl = lane % L;
  int sub = lane / L;

  float xr[4];
  load_bf4(&XR[(size_t)v * H + fl * 4], xr);
  const float4 a4 = *reinterpret_cast<const float4*>(&att[fl * 4]);
  int beg = rp[v], end = rp[v + 1];

  float mA = -3.0e38f, dA = 0.f, accA[4] = {0.f, 0.f, 0.f, 0.f};
  float mB = -3.0e38f, dB = 0.f, accB[4] = {0.f, 0.f, 0.f, 0.f};

  auto edge = [&](int j, float& m, float& d, float (&acc)[4]) {
    int u = ssrc[j];
    float xl[4];
    load_bf4(&XL[(size_t)u * H + fl * 4], xl);
    float t = a4.x * lrelu02(xl[0] + xr[0]);
    t = fmaf(a4.y, lrelu02(xl[1] + xr[1]), t);
    t = fmaf(a4.z, lrelu02(xl[2] + xr[2]), t);
    t = fmaf(a4.w, lrelu02(xl[3] + xr[3]), t);
#pragma unroll
    for (int o = L / 2; o >= 1; o >>= 1) t += __shfl_xor(t, o);
    float diff = t - m;
    if (diff > 8.f) {
      float sc = __expf(-diff);
      d *= sc;
#pragma unroll
      for (int e = 0; e < 4; e++) acc[e] *= sc;
      m = t; diff = 0.f;
    }
    float w = __expf(diff);
    d += w;
#pragma unroll
    for (int e = 0; e < 4; e++) acc[e] = fmaf(w, xl[e], acc[e]);
  };

  for (int j = beg + sub; j < end; j += STEP) {
    edge(j, mA, dA, accA);
    int j2 = j + C;
    if (j2 < end) edge(j2, mB, dB, accB);
  }

  {
    float mn = fmaxf(mA, mB);
    float s1 = __expf(mA - mn), s2 = __expf(mB - mn);
    dA = dA * s1 + dB * s2;
#pragma unroll
    for (int e = 0; e < 4; e++) accA[e] = accA[e] * s1 + accB[e] * s2;
    mA = mn;
  }

#pragma unroll
  for (int o = L; o < 64; o <<= 1) {
    float mo = __shfl_xor(mA, o);
    float d2 = __shfl_xor(dA, o);
    float a0 = __shfl_xor(accA[0], o);
    float a1 = __shfl_xor(accA[1], o);
    float a2 = __shfl_xor(accA[2], o);
    float a3 = __shfl_xor(accA[3], o);
    float mn = fmaxf(mA, mo);
    float s1 = __expf(mA - mn), s2 = __expf(mo - mn);
    dA = dA * s1 + d2 * s2;
    accA[0] = accA[0] * s1 + a0 * s2;
    accA[1] = accA[1] * s1 + a1 * s2;
    accA[2] = accA[2] * s1 + a2 * s2;
    accA[3] = accA[3] * s1 + a3 * s2;
    mA = mn;
  }

  if (lane < L) {
    float inv = 1.f / (dA + 1e-16f);
    const float4 b4 = *reinterpret_cast<const float4*>(&bias[fl * 4]);
    float4 o4 = make_float4(fmaf(accA[0], inv, b4.x), fmaf(accA[1], inv, b4.y),
                            fmaf(accA[2], inv, b4.z), fmaf(accA[3], inv, b4.w));
    *reinterpret_cast<float4*>(&out[(size_t)v * H + fl * 4]) = o4;
  }
}

// v6 (H=32/16): register-buffered chunks.
template <int H, int ITER>
__global__ __launch_bounds__(256) void gat_agg6(
    const unsigned short* __restrict__ XL, const unsigned short* __restrict__ XR,
    const float* __restrict__ att, const float* __restrict__ bias,
    const int* __restrict__ rp, const int* __restrict__ ssrc,
    float* __restrict__ out, int N) {
  constexpr int L = H / 4;
  constexpr int C = 64 / L;
  constexpr int CHUNK = C * ITER;
  int v = blockIdx.x * 4 + (threadIdx.x >> 6);
  if (v >= N) return;
  int lane = threadIdx.x & 63;
  int fl = lane % L;
  int sub = lane / L;

  float xr[4];
  load_bf4(&XR[(size_t)v * H + fl * 4], xr);
  const float4 a4 = *reinterpret_cast<const float4*>(&att[fl * 4]);
  int beg = rp[v], end = rp[v + 1];

  float m = -3.0e38f, d = 0.f, acc[4] = {0.f, 0.f, 0.f, 0.f};

  for (int cb = beg; cb < end; cb += CHUNK) {
    float xb[ITER][4];
    float tl[ITER];
    float mc = -3.0e38f;
#pragma unroll
    for (int it = 0; it < ITER; it++) {
      int j = cb + it * C + sub;
      bool valid = (j < end);
      int jj = valid ? j : (end - 1);
      int u = ssrc[jj];
      load_bf4(&XL[(size_t)u * H + fl * 4], xb[it]);
      float t = a4.x * lrelu02(xb[it][0] + xr[0]);
      t = fmaf(a4.y, lrelu02(xb[it][1] + xr[1]), t);
      t = fmaf(a4.z, lrelu02(xb[it][2] + xr[2]), t);
      t = fmaf(a4.w, lrelu02(xb[it][3] + xr[3]), t);
#pragma unroll
      for (int o = L / 2; o >= 1; o >>= 1) t += __shfl_xor(t, o);
      tl[it] = valid ? t : -3.0e38f;
      mc = fmaxf(mc, tl[it]);
    }
#pragma unroll
    for (int o = L; o < 64; o <<= 1) mc = fmaxf(mc, __shfl_xor(mc, o));

    float mn = fmaxf(m, mc);
    float sc = __expf(m - mn);
    d *= sc;
#pragma unroll
    for (int e = 0; e < 4; e++) acc[e] *= sc;
    m = mn;

#pragma unroll
    for (int it = 0; it < ITER; it++) {
      float w = __expf(tl[it] - m);
      d += w;
#pragma unroll
      for (int e = 0; e < 4; e++) acc[e] = fmaf(w, xb[it][e], acc[e]);
    }
  }

#pragma unroll
  for (int o = L; o < 64; o <<= 1) {
    d += __shfl_xor(d, o);
#pragma unroll
    for (int e = 0; e < 4; e++) acc[e] += __shfl_xor(acc[e], o);
  }

  if (lane < L) {
    float inv = 1.f / (d + 1e-16f);
    const float4 b4 = *reinterpret_cast<const float4*>(&bias[fl * 4]);
    float4 o4 = make_float4(fmaf(acc[0], inv, b4.x), fmaf(acc[1], inv, b4.y),
                            fmaf(acc[2], inv, b4.z), fmaf(acc[3], inv, b4.w));
    *reinterpret_cast<float4*>(&out[(size_t)v * H + fl * 4]) = o4;
  }
}

// ---------------- BatchNorm ----------------
template <int H>
__global__ __launch_bounds__(256) void bn_stats(
    const float* __restrict__ X, float* __restrict__ stats, int N) {
  __shared__ float ls[256], ls2[256];
  int tid = threadIdx.x;
  int h = tid % H;
  constexpr int RPB = 256 / H;
  int r0 = blockIdx.x * RPB + tid / H;
  float s = 0.f, s2 = 0.f;
  for (int n = r0; n < N; n += gridDim.x * RPB) {
    float val = X[(size_t)n * H + h];
    s += val; s2 += val * val;
  }
  ls[tid] = s; ls2[tid] = s2;
  __syncthreads();
  if (tid < H) {
    for (int g = 1; g < RPB; g++) { s += ls[tid + g * H]; s2 += ls2[tid + g * H]; }
    atomicAdd(&stats[h], s);
    atomicAdd(&stats[H + h], s2);
  }
}

__global__ void bn_finalize(
    const float* __restrict__ stats, const float* __restrict__ gamma,
    const float* __restrict__ beta, float* __restrict__ ss, int H, int N) {
  int h = threadIdx.x;
  if (h < H) {
    float mean = stats[h] / (float)N;
    float var = stats[H + h] / (float)N - mean * mean;
    float istd = rsqrtf(var + 1e-5f);
    float sc = gamma[h] * istd;
    ss[h] = sc;
    ss[H + h] = beta[h] - mean * sc;
  }
}

// ---------------- fused BN+ReLU + mean-pool, then final linear ------------
__global__ __launch_bounds__(256) void pool_kernel(
    const float* __restrict__ X, const float* __restrict__ ss,
    const int* __restrict__ batch, float* __restrict__ pool,
    float* __restrict__ cnt, int N) {
  __shared__ float lp[G_ * 16];
  __shared__ float lc[G_];
  int tid = threadIdx.x;
  for (int j = tid; j < G_ * 16; j += 256) lp[j] = 0.f;
  if (tid < G_) lc[tid] = 0.f;
  __syncthreads();
  int tot = N * 16;
  for (int i = blockIdx.x * 256 + tid; i < tot; i += gridDim.x * 256) {
    int n = i >> 4, h = i & 15;
    int g = batch[n];
    float t = X[i] * ss[h] + ss[16 + h];
    t = (t > 0.f) ? t : 0.f;
    atomicAdd(&lp[g * 16 + h], t);
    if (h == 0) atomicAdd(&lc[g], 1.0f);
  }
  __syncthreads();
  for (int j = tid; j < G_ * 16; j += 256) atomicAdd(&pool[j], lp[j]);
  if (tid < G_) atomicAdd(&cnt[tid], lc[tid]);
}

__global__ void final_linear(
    const float* __restrict__ pool, const float* __restrict__ cnt,
    const float* __restrict__ linW, const float* __restrict__ linb,
    float* __restrict__ out) {
  int g = threadIdx.x;
  if (g < G_) {
    float c = fmaxf(cnt[g], 1.0f);
    float acc = 0.f;
    for (int h = 0; h < 16; h++) acc += (pool[g * 16 + h] / c) * linW[h];
    out[g] = acc + linb[0];
  }
}

// ---------------- launch ----------------
extern "C" void kernel_launch(void* const* d_in, const int* in_sizes, int n_in,
                              void* d_out, int out_size, void* d_ws, size_t ws_size,
                              hipStream_t stream) {
  const float* x = (const float*)d_in[0];
  const int* ei = (const int*)d_in[1];
  const int* batch = (const int*)d_in[2];
  const int N = in_sizes[0] / 128;
  const int E = in_sizes[1] / 2;
  const int Etot = E + N;

  char* wsb = (char*)d_ws;
  size_t off = 0;
  auto alloc = [&](size_t bytes) -> void* {
    void* p = wsb + off;
    off += (bytes + 255) & ~(size_t)255;
    return p;
  };
  unsigned short* XLb = (unsigned short*)alloc((size_t)64 * N * 2);  // xl bf16
  unsigned short* XRb = (unsigned short*)alloc((size_t)64 * N * 2);  // xr bf16
  float* R2 = (float*)alloc((size_t)64 * N * 4);                     // agg out fp32
  int* row_ptr = (int*)alloc((size_t)(N + 1) * 4);
  int* cursor = (int*)alloc((size_t)N * 4);
  int* bsums = (int*)alloc(4096);
  int* ssrc = (int*)alloc((size_t)Etot * 4);
  unsigned short* Wt1 = (unsigned short*)alloc(16384 * 2);
  float* bc1 = (float*)alloc(128 * 4);
  unsigned short* Wt2 = (unsigned short*)alloc(4096 * 2);
  float* bc2 = (float*)alloc(64 * 4);
  unsigned short* Wt3 = (unsigned short*)alloc(1024 * 2);
  float* bc3 = (float*)alloc(32 * 4);
  float* ss = (float*)alloc(256 * 4);
  // zeroed region: deg[N] | stats1[128] | stats2[128] | stats3[128] | pool | cnt
  size_t zelems = (size_t)N + 3 * 128 + G_ * 16 + G_;
  char* zb = (char*)alloc(zelems * 4);
  int* deg = (int*)zb;
  float* stats1 = (float*)(zb + (size_t)N * 4);
  float* stats2 = stats1 + 128;
  float* stats3 = stats2 + 128;
  float* pool = stats3 + 128;
  float* cnt = pool + G_ * 16;

  const float* Wl1 = (const float*)d_in[3];  const float* bl1 = (const float*)d_in[4];
  const float* Wr1 = (const float*)d_in[5];  const float* br1 = (const float*)d_in[6];
  const float* att1 = (const float*)d_in[7]; const float* bias1 = (const float*)d_in[8];
  const float* g1 = (const float*)d_in[9];   const float* b1 = (const float*)d_in[10];
  const float* Wl2 = (const float*)d_in[11]; const float* bl2 = (const float*)d_in[12];
  const float* Wr2 = (const float*)d_in[13]; const float* br2 = (const float*)d_in[14];
  const float* att2 = (const float*)d_in[15]; const float* bias2 = (const float*)d_in[16];
  const float* g2 = (const float*)d_in[17];  const float* b2 = (const float*)d_in[18];
  const float* Wl3 = (const float*)d_in[19]; const float* bl3 = (const float*)d_in[20];
  const float* Wr3 = (const float*)d_in[21]; const float* br3 = (const float*)d_in[22];
  const float* att3 = (const float*)d_in[23]; const float* bias3 = (const float*)d_in[24];
  const float* g3 = (const float*)d_in[25];  const float* b3 = (const float*)d_in[26];
  const float* linW = (const float*)d_in[27]; const float* linb = (const float*)d_in[28];
  float* out = (float*)d_out;

  int nb = (N + 1023) / 1024;
  int nnodeblk = (N + 3) / 4;
  int ngemm = (N + 63) / 64;

  // weights + zero scratch
  pack_all<<<64, 256, 0, stream>>>(Wl1, Wr1, bl1, br1, Wl2, Wr2, bl2, br2,
                                   Wl3, Wr3, bl3, br3, Wt1, bc1, Wt2, bc2, Wt3, bc3);
  hipMemsetAsync(zb, 0, zelems * 4, stream);

  // CSR build (XCD-partitioned hist + scatter)
  edge_hist<<<4096, 256, 0, stream>>>(ei, deg, E, Etot, N);
  scan1<<<nb, 256, 0, stream>>>(deg, row_ptr, bsums, N);
  scan2<<<1, 256, 0, stream>>>(bsums, nb);
  scan3<<<(N + 255) / 256, 256, 0, stream>>>(row_ptr, cursor, bsums, N, Etot);
  scatter_edges<<<4096, 256, 0, stream>>>(ei, cursor, ssrc, E, Etot, N);

  // ---- layer 1 ----
  gemm_mfma<128, 128, 1><<<ngemm, 256, 0, stream>>>(x, nullptr, Wt1, bc1, XLb, XRb, N);
  gat_agg4<64><<<nnodeblk, 256, 0, stream>>>(XLb, XRb, att1, bias1, row_ptr, ssrc, R2, N);
  bn_stats<64><<<512, 256, 0, stream>>>(R2, stats1, N);
  bn_finalize<<<1, 64, 0, stream>>>(stats1, g1, b1, ss, 64, N);

  // ---- layer 2 (BN+ReLU fused into GEMM A-load) ----
  gemm_mfma<64, 64, 2><<<ngemm, 256, 0, stream>>>(R2, ss, Wt2, bc2, XLb, XRb, N);
  gat_agg6<32, 4><<<nnodeblk, 256, 0, stream>>>(XLb, XRb, att2, bias2, row_ptr, ssrc, R2, N);
  bn_stats<32><<<512, 256, 0, stream>>>(R2, stats2, N);
  bn_finalize<<<1, 64, 0, stream>>>(stats2, g2, b2, ss, 32, N);

  // ---- layer 3 ----
  gemm_mfma<32, 32, 2><<<ngemm, 256, 0, stream>>>(R2, ss, Wt3, bc3, XLb, XRb, N);
  gat_agg6<16, 2><<<nnodeblk, 256, 0, stream>>>(XLb, XRb, att3, bias3, row_ptr, ssrc, R2, N);
  bn_stats<16><<<512, 256, 0, stream>>>(R2, stats3, N);
  bn_finalize<<<1, 64, 0, stream>>>(stats3, g3, b3, ss, 16, N);

  // ---- fused BN+ReLU+pool + linear ----
  pool_kernel<<<2048, 256, 0, stream>>>(R2, ss, batch, pool, cnt, N);
  final_linear<<<1, 64, 0, stream>>>(pool, cnt, linW, linb, out);
}